// Round 4
// baseline (488.239 us; speedup 1.0000x reference)
//
#include <hip/hip_runtime.h>
#include <math.h>

typedef float v4 __attribute__((ext_vector_type(4)));
typedef float f32x4 __attribute__((ext_vector_type(4)));
typedef __bf16 bf16x8 __attribute__((ext_vector_type(8)));

#define HD 1024      // hidden dim
#define NB 64        // batch

// ws layout (float offsets)
#define WS_IGT  0         // igT [1024][64]   exp(i-gate), transposed
#define WS_FGT  65536     // fgT [1024][64]   exp(f-gate)
#define WS_QT   131072    // qT  [1024][64]
#define WS_VT   196608    // vT  [1024][64]
#define WS_OGN  262144    // ogN [64][1024]   sigmoid(o), natural
#define WS_KN   327680    // kN  [64][1024]   natural
#define WS_BPK  393216    // bf16 x/h B-fragments [64 ks][4 bt][64 lane][8] = 65536 floats
#define WS_PART 458752    // readout partials [32 c][64 b][1024] = 2,097,152 floats
#define WS_PG   2555904   // gates partials [16 c][192 t][16 r][64 b] = 3,145,728 floats
#define WS_PQ   5701632   // qkv  partials [ 8 c][192 t][16 r][64 b] = 1,572,864 floats
// total = 7,274,496 floats = 29.1 MB

// ---------------- kernel 1: pack x/h to bf16 MFMA B-fragments (tiny) ------------
// B-fragment (mfma_f32_16x16x32_bf16): lane l holds X[bt*16 + (l&15)][ks*32 + (l>>4)*8 + j]
// ks 0..31 = input, ks 32..63 = h. Layout verified round-2/3.
__global__ __launch_bounds__(256) void k_prepb(const float* __restrict__ input,
                                               const float* __restrict__ h,
                                               float* __restrict__ ws) {
    int o = blockIdx.x * 256 + threadIdx.x;     // 0..16383
    int l  = o & 63;
    int bt = (o >> 6) & 3;
    int ks = o >> 8;                            // 0..63
    const float* srcm = (ks < 32) ? input : h;
    const float* src = srcm + (size_t)(bt * 16 + (l & 15)) * HD + (ks & 31) * 32 + (l >> 4) * 8;
    v4 f0 = *(const v4*)src;
    v4 f1 = *(const v4*)(src + 4);
    bf16x8 pk;
    pk[0] = (__bf16)f0.x; pk[1] = (__bf16)f0.y; pk[2] = (__bf16)f0.z; pk[3] = (__bf16)f0.w;
    pk[4] = (__bf16)f1.x; pk[5] = (__bf16)f1.y; pk[6] = (__bf16)f1.z; pk[7] = (__bf16)f1.w;
    *((bf16x8*)((__bf16*)(ws + WS_BPK)) + o) = pk;
}

// ---------------- kernel 2: MFMA GEMM, K-chunked, fp32-direct A loads -----------
// One wave = one 16-row tile x 64 batch x K-chunk of 128 (4 ksteps of 32).
// A loaded fp32 straight from HBM (A-fragment = 32B of one weight row per lane,
// coalesced), converted in-register -> no weight repack, weights stream once.
// gates: 192 tiles x 16 chunks = 3072 waves (chunks 0..7 = Wih/x, 8..15 = Whh/h)
// qkv:   192 tiles x  8 chunks = 1536 waves
// total 4608 waves = 1152 blocks -> 18 waves/CU (round-2-proven latency hiding).
__global__ __launch_bounds__(256) void k_mfma(
    const float* __restrict__ Wih, const float* __restrict__ Whh,
    const float* __restrict__ Wq, const float* __restrict__ Wk, const float* __restrict__ Wv,
    float* __restrict__ ws) {
    int lane = threadIdx.x & 63;
    int w = blockIdx.x * 4 + (threadIdx.x >> 6);
    const bf16x8* Bp = (const bf16x8*)((const __bf16*)(ws + WS_BPK));

    const float* wrow;
    float* pout;
    int ksB;
    if (w < 3072) {
        int t = w >> 4, c = w & 15;
        const float* Wb = (c < 8) ? Wih : Whh;
        int kk0 = (c & 7) * 128;                 // fp32 col offset within W
        wrow = Wb + (size_t)(t * 16 + (lane & 15)) * HD + kk0 + (lane >> 4) * 8;
        pout = ws + WS_PG + (size_t)(c * 192 + t) * 1024;
        ksB  = c * 4;                            // global kstep (0..31 x, 32..63 h)
    } else {
        int w2 = w - 3072;
        int t = w2 >> 3, c = w2 & 7;
        int sel = t >> 6;
        const float* W = (sel == 0) ? Wq : (sel == 1) ? Wk : Wv;
        wrow = W + (size_t)((t & 63) * 16 + (lane & 15)) * HD + c * 128 + (lane >> 4) * 8;
        pout = ws + WS_PQ + (size_t)(c * 192 + t) * 1024;
        ksB  = c * 4;
    }

    f32x4 a0 = {0.f, 0.f, 0.f, 0.f};
    f32x4 a1 = a0, a2 = a0, a3 = a0;
    #pragma unroll
    for (int s = 0; s < 4; ++s) {
        const float* ap = wrow + s * 32;
        v4 f0 = *(const v4*)ap;
        v4 f1 = *(const v4*)(ap + 4);
        bf16x8 a;
        a[0] = (__bf16)f0.x; a[1] = (__bf16)f0.y; a[2] = (__bf16)f0.z; a[3] = (__bf16)f0.w;
        a[4] = (__bf16)f1.x; a[5] = (__bf16)f1.y; a[6] = (__bf16)f1.z; a[7] = (__bf16)f1.w;
        const bf16x8* bb = Bp + (size_t)(ksB + s) * 256 + lane;
        bf16x8 b0 = bb[0], b1 = bb[64], b2 = bb[128], b3 = bb[192];
        a0 = __builtin_amdgcn_mfma_f32_16x16x32_bf16(a, b0, a0, 0, 0, 0);
        a1 = __builtin_amdgcn_mfma_f32_16x16x32_bf16(a, b1, a1, 0, 0, 0);
        a2 = __builtin_amdgcn_mfma_f32_16x16x32_bf16(a, b2, a2, 0, 0, 0);
        a3 = __builtin_amdgcn_mfma_f32_16x16x32_bf16(a, b3, a3, 0, 0, 0);
    }
    // C/D layout: col = lane&15, row = (lane>>4)*4 + reg  (verified round-2)
    int rb = (lane >> 4) * 4, cb = lane & 15;
    #pragma unroll
    for (int q = 0; q < 4; ++q) {
        pout[(rb + q) * 64 +  0 + cb] = a0[q];
        pout[(rb + q) * 64 + 16 + cb] = a1[q];
        pout[(rb + q) * 64 + 32 + cb] = a2[q];
        pout[(rb + q) * 64 + 48 + cb] = a3[q];
    }
}

// ---------------- kernel 3: reduce partials + bias + activations ----------------
__global__ __launch_bounds__(256) void k_act(
    const float* __restrict__ bias,
    const float* __restrict__ Wqb, const float* __restrict__ Wkb, const float* __restrict__ Wvb,
    float* __restrict__ ws) {
    int g = blockIdx.x * 256 + threadIdx.x;   // 0..393215
    if (g < 196608) {
        int r = g >> 6, b = g & 63;
        int t = r >> 4, ro = r & 15;
        const float* P = ws + WS_PG + ro * 64 + b;
        float s = bias[r];
        #pragma unroll
        for (int c = 0; c < 16; ++c) s += P[(size_t)(c * 192 + t) * 1024];
        if (r < 1024)       ws[WS_IGT + r * 64 + b] = expf(s);
        else if (r < 2048)  ws[WS_FGT + (r - 1024) * 64 + b] = expf(s);
        else                ws[WS_OGN + b * HD + (r - 2048)] = 1.f / (1.f + expf(-s));
    } else {
        int e = g - 196608;
        int r2 = e >> 6, b = e & 63;
        int t = r2 >> 4, ro = r2 & 15;
        int sel = r2 >> 10, rr = r2 & 1023;
        const float* P = ws + WS_PQ + ro * 64 + b;
        float s = ((sel == 0) ? Wqb : (sel == 1) ? Wkb : Wvb)[rr];
        #pragma unroll
        for (int c = 0; c < 8; ++c) s += P[(size_t)(c * 192 + t) * 1024];
        if (sel == 0)      ws[WS_QT + rr * 64 + b] = s;
        else if (sel == 1) ws[WS_KN + b * HD + rr] = s;
        else               ws[WS_VT + rr * 64 + b] = s;
    }
}

// ---------------- kernel 4: C update + fused readout partials (round-3 body) ----
__global__ __launch_bounds__(256) void k_update(const float* __restrict__ C,
                                                float* __restrict__ out,
                                                float* __restrict__ ws) {
    int b  = blockIdx.x >> 5;
    int c  = blockIdx.x & 31;
    int i0 = c << 5;
    int tid = threadIdx.x;

    __shared__ float fg_s[32], iv_s[32], q_s[32];
    if (tid < 32) {
        int i = i0 + tid;
        fg_s[tid] = ws[WS_FGT + i * 64 + b];
        iv_s[tid] = ws[WS_IGT + i * 64 + b] * ws[WS_VT + i * 64 + b];
        q_s[tid]  = ws[WS_QT + i * 64 + b];
    }
    __syncthreads();

    v4 k4 = *(const v4*)(ws + WS_KN + b * HD + tid * 4);
    const v4* Cb = (const v4*)(C + (size_t)b * HD * HD) + tid;
    v4*       On = (v4*)(out + NB * HD + (size_t)b * HD * HD) + tid;
    v4 acc0 = {0.f, 0.f, 0.f, 0.f};
    v4 acc1 = {0.f, 0.f, 0.f, 0.f};

    #pragma unroll
    for (int ii = 0; ii < 32; ii += 4) {
        size_t r0 = (size_t)(i0 + ii) * 256;
        v4 c0 = __builtin_nontemporal_load(&Cb[r0]);
        v4 c1 = __builtin_nontemporal_load(&Cb[r0 + 256]);
        v4 c2 = __builtin_nontemporal_load(&Cb[r0 + 512]);
        v4 c3 = __builtin_nontemporal_load(&Cb[r0 + 768]);

        float f0 = fg_s[ii + 0], g0 = iv_s[ii + 0], q0 = q_s[ii + 0];
        float f1 = fg_s[ii + 1], g1 = iv_s[ii + 1], q1 = q_s[ii + 1];
        float f2 = fg_s[ii + 2], g2 = iv_s[ii + 2], q2 = q_s[ii + 2];
        float f3 = fg_s[ii + 3], g3 = iv_s[ii + 3], q3 = q_s[ii + 3];

        v4 n0, n1, n2, n3;
        n0.x = f0 * c0.x + g0 * k4.x; n0.y = f0 * c0.y + g0 * k4.y;
        n0.z = f0 * c0.z + g0 * k4.z; n0.w = f0 * c0.w + g0 * k4.w;
        n1.x = f1 * c1.x + g1 * k4.x; n1.y = f1 * c1.y + g1 * k4.y;
        n1.z = f1 * c1.z + g1 * k4.z; n1.w = f1 * c1.w + g1 * k4.w;
        n2.x = f2 * c2.x + g2 * k4.x; n2.y = f2 * c2.y + g2 * k4.y;
        n2.z = f2 * c2.z + g2 * k4.z; n2.w = f2 * c2.w + g2 * k4.w;
        n3.x = f3 * c3.x + g3 * k4.x; n3.y = f3 * c3.y + g3 * k4.y;
        n3.z = f3 * c3.z + g3 * k4.z; n3.w = f3 * c3.w + g3 * k4.w;

        __builtin_nontemporal_store(n0, &On[r0]);
        __builtin_nontemporal_store(n1, &On[r0 + 256]);
        __builtin_nontemporal_store(n2, &On[r0 + 512]);
        __builtin_nontemporal_store(n3, &On[r0 + 768]);

        acc0.x += q0 * n0.x; acc0.y += q0 * n0.y; acc0.z += q0 * n0.z; acc0.w += q0 * n0.w;
        acc1.x += q1 * n1.x; acc1.y += q1 * n1.y; acc1.z += q1 * n1.z; acc1.w += q1 * n1.w;
        acc0.x += q2 * n2.x; acc0.y += q2 * n2.y; acc0.z += q2 * n2.z; acc0.w += q2 * n2.w;
        acc1.x += q3 * n3.x; acc1.y += q3 * n3.y; acc1.z += q3 * n3.z; acc1.w += q3 * n3.w;
    }
    v4 acc;
    acc.x = acc0.x + acc1.x; acc.y = acc0.y + acc1.y;
    acc.z = acc0.z + acc1.z; acc.w = acc0.w + acc1.w;
    *(v4*)(ws + WS_PART + (size_t)(c * 64 + b) * HD + tid * 4) = acc;
}

// ---------------- kernel 5: finalize h ------------------------------------------
__global__ __launch_bounds__(256) void k_final(float* __restrict__ out,
                                               const float* __restrict__ ws) {
    int b = blockIdx.x;
    int tid = threadIdx.x;
    const v4* part = (const v4*)(ws + WS_PART);
    v4 s = {0.f, 0.f, 0.f, 0.f};
    #pragma unroll 4
    for (int c = 0; c < 32; ++c) {
        v4 p = part[(size_t)(c * 64 + b) * 256 + tid];
        s.x += p.x; s.y += p.y; s.z += p.z; s.w += p.w;
    }
    v4 o4 = *(const v4*)(ws + WS_OGN + b * HD + tid * 4);
    v4 r;
    r.x = o4.x * s.x; r.y = o4.y * s.y; r.z = o4.z * s.z; r.w = o4.w * s.w;
    *(v4*)(out + b * HD + tid * 4) = r;
}

extern "C" void kernel_launch(void* const* d_in, const int* in_sizes, int n_in,
                              void* d_out, int out_size, void* d_ws, size_t ws_size,
                              hipStream_t stream) {
    const float* input = (const float*)d_in[0];
    const float* h     = (const float*)d_in[1];
    const float* C     = (const float*)d_in[2];
    const float* Wih   = (const float*)d_in[3];
    const float* Whh   = (const float*)d_in[4];
    const float* bias  = (const float*)d_in[5];
    const float* Wq_w  = (const float*)d_in[6];
    const float* Wq_b  = (const float*)d_in[7];
    const float* Wk_w  = (const float*)d_in[8];
    const float* Wk_b  = (const float*)d_in[9];
    const float* Wv_w  = (const float*)d_in[10];
    const float* Wv_b  = (const float*)d_in[11];
    float* out = (float*)d_out;
    float* ws  = (float*)d_ws;

    k_prepb<<<64, 256, 0, stream>>>(input, h, ws);
    k_mfma<<<1152, 256, 0, stream>>>(Wih, Whh, Wq_w, Wk_w, Wv_w, ws);
    k_act<<<1536, 256, 0, stream>>>(bias, Wq_b, Wk_b, Wv_b, ws);
    k_update<<<2048, 256, 0, stream>>>(C, out, ws);
    k_final<<<64, 256, 0, stream>>>(out, ws);
}